// Round 16
// baseline (173.118 us; speedup 1.0000x reference)
//
#include <hip/hip_runtime.h>

// FeatureAdaptation (deformable conv): B=2, CHI=CHO=256, H=W=128, K=9.
// R16: lockstep cache-sharing. Same per-wave tile as R15 (16 px x 256 oc,
// producer==consumer, zero cross-thread staging) but 4-wave blocks over
// ADJACENT pixel groups + per-tap __syncthreads so the 8 waves/CU stream B
// (and overlapping A corner lines) through L1 together instead of 8 separate
// L2 passes. Barrier only orders execution: no LDS writes in the loop.

typedef __bf16 bf16x8 __attribute__((ext_vector_type(8)));
typedef float f32x4 __attribute__((ext_vector_type(4)));

#define HH 128
#define WW 128
#define CIN 256
#define COUT 256
#define KK9 9
#define HW (HH * WW)            // 16384
#define KDIM (KK9 * CIN)        // 2304
#define XT_PER_B (HW * CIN)

__device__ __forceinline__ ushort f2bf(float f) {
  union { float f; unsigned u; } v; v.f = f;
  unsigned u = v.u;
  u += 0x7FFFu + ((u >> 16) & 1u);   // RNE
  return (ushort)(u >> 16);
}
__device__ __forceinline__ float bf2f(ushort h) {
  return __uint_as_float(((unsigned)h) << 16);
}
// bf16 element e (0..7) of an int4 viewed as 8 bf16, as f32 (e compile-time)
__device__ __forceinline__ float bfsel(const int4 v, int e) {
  int w = ((e >> 1) == 0) ? v.x : ((e >> 1) == 1) ? v.y
        : ((e >> 1) == 2) ? v.z : v.w;
  return __uint_as_float((e & 1) ? ((unsigned)w & 0xffff0000u)
                                 : ((unsigned)w << 16));
}
__device__ __forceinline__ int packpair(const float4 wt, const int4 a0,
                                        const int4 a1, const int4 a2,
                                        const int4 a3, int q) {
  float vl = wt.x * bfsel(a0, 2 * q)     + wt.y * bfsel(a1, 2 * q)
           + wt.z * bfsel(a2, 2 * q)     + wt.w * bfsel(a3, 2 * q);
  float vh = wt.x * bfsel(a0, 2 * q + 1) + wt.y * bfsel(a1, 2 * q + 1)
           + wt.z * bfsel(a2, 2 * q + 1) + wt.w * bfsel(a3, 2 * q + 1);
  return (int)((unsigned)f2bf(vl) | ((unsigned)f2bf(vh) << 16));
}

// ---------------- x (B,C,H,W) f32  ->  xT (B,H,W,C) bf16 ----------------
__global__ __launch_bounds__(256) void k_transpose(const float* __restrict__ x,
                                                   ushort* __restrict__ xT) {
  __shared__ ushort tile[64][130];
  const int bid = blockIdx.x;
  const int y  = bid & 127;
  const int t  = bid >> 7;
  const int cb = t & 3;
  const int b  = t >> 2;
  const int xl = threadIdx.x & 127;
  const int ch = threadIdx.x >> 7;
  const float* src = x + (size_t)(b * CIN + cb * 64) * HW + y * WW + xl;
#pragma unroll
  for (int i = 0; i < 32; ++i) {
    int c = ch * 32 + i;
    tile[c][xl] = f2bf(src[(size_t)c * HW]);
  }
  __syncthreads();
  const int c  = threadIdx.x & 63;
  const int xh = threadIdx.x >> 6;
  ushort* dst = xT + (size_t)b * XT_PER_B + (size_t)(y * WW) * CIN + cb * 64 + c;
#pragma unroll
  for (int i = 0; i < 32; ++i) {
    int xx = xh * 32 + i;
    dst[(size_t)xx * CIN] = tile[c][xx];
  }
}

// ------- conv_w (O,C,3,3) -> Bm2 fragment-linear bf16 (R15-verified) -------
__global__ __launch_bounds__(256) void k_packw2(const float* __restrict__ cw,
                                                ushort* __restrict__ Bm2) {
  int idx = blockIdx.x * 256 + threadIdx.x;   // < 589824
  int e  = idx & 7;
  int l  = (idx >> 3) & 63;
  int f  = idx >> 9;          // frag id: (s*16 + ni), s = t*8+cc
  int ni = f & 15;
  int s  = f >> 4;            // 0..71
  int cc = s & 7;
  int t  = s >> 3;
  int nl = l & 15;
  int kg = l >> 4;
  int o  = ni * 16 + nl;
  int c  = cc * 32 + kg * 8 + e;
  Bm2[idx] = f2bf(cw[(o * CIN + c) * KK9 + t]);
}

// ---------------- lockstep 4-wave gather + implicit MFMA GEMM ----------------
// grid 512 (XCD-swizzled); block 256 (4 waves). Block: 64 adjacent px x 256 oc;
// wave wid owns px [wid*16, wid*16+16). No cross-thread staging anywhere.
__global__ __launch_bounds__(256) void k_mfma8(
    const ushort* __restrict__ xT, const ushort* __restrict__ Bm2,
    const float* __restrict__ scale, const float* __restrict__ ctr,
    const float* __restrict__ offw, const float* __restrict__ offb,
    const float* __restrict__ mskw, const float* __restrict__ mskb,
    const float* __restrict__ convb, float* __restrict__ out) {
  __shared__ int4   moff[64 * KK9];
  __shared__ float4 mwt[64 * KK9];

  const int tid  = threadIdx.x;
  const int lane = tid & 63;
  const int wid  = tid >> 6;
  // bijective XCD swizzle (512 % 8 == 0): XCD x owns a contiguous mb band
  const int mb  = ((blockIdx.x & 7) << 6) | (blockIdx.x >> 3);
  const int b   = mb >> 8;
  const int rem = mb & 255;
  const int h   = rem >> 1;
  const int w0  = (rem & 1) << 6;   // 64-pixel row segment

  // ---- prologue: per (pixel,tap) bilinear metadata (R2-verified math)
  for (int idx = tid; idx < 64 * KK9; idx += 256) {
    int p = idx / 9;
    int k = idx - p * 9;
    int w = w0 + p;
    float sc = scale[b * HW + h * WW + w];
    float ct = ctr[b * HW + h * WW + w];
    float dy = sc * offw[2 * k]     + offb[2 * k];
    float dx = sc * offw[2 * k + 1] + offb[2 * k + 1];
    float mk = 1.0f / (1.0f + __expf(-(ct * mskw[k] + mskb[k])));
    float ys = (float)(h + (k / 3) - 1) + dy;
    float xs = (float)(w + (k % 3) - 1) + dx;
    float y0 = floorf(ys), x0 = floorf(xs);
    float wy1 = ys - y0, wx1 = xs - x0;
    float wy0 = 1.f - wy1, wx0 = 1.f - wx1;
    int offc[4]; float wtc[4];
#pragma unroll
    for (int a = 0; a < 2; ++a)
#pragma unroll
      for (int bb = 0; bb < 2; ++bb) {
        float yc = y0 + (float)a, xc = x0 + (float)bb;
        bool valid = (yc >= 0.f) && (yc <= 127.f) && (xc <= 127.f) && (xc >= 0.f);
        int yi = (int)fminf(fmaxf(yc, 0.f), 127.f);
        int xi = (int)fminf(fmaxf(xc, 0.f), 127.f);
        offc[a * 2 + bb] = (yi * WW + xi) * CIN;
        wtc[a * 2 + bb]  = (a ? wy1 : wy0) * (bb ? wx1 : wx0) * mk * (valid ? 1.f : 0.f);
      }
    moff[idx] = make_int4(offc[0], offc[1], offc[2], offc[3]);
    mwt[idx]  = make_float4(wtc[0], wtc[1], wtc[2], wtc[3]);
  }
  __syncthreads();

  const ushort* xTb = xT + (size_t)b * XT_PER_B;
  const int nl  = lane & 15;
  const int kg  = lane >> 4;
  const int kg8 = kg * 8;
  const int px  = wid * 16 + nl;    // my pixel within the block's 64

  f32x4 acc[16];
#pragma unroll
  for (int ni = 0; ni < 16; ++ni) acc[ni] = (f32x4){0.f, 0.f, 0.f, 0.f};

  // per-lane B base: fragment-linear (R15-verified), all waves share this stream
  const ushort* bpl = Bm2 + (size_t)lane * 8;

  for (int t = 0; t < KK9; ++t) {
    const int4   mo = moff[px * 9 + t];      // my pixel's 4 corner offsets
    const float4 wt = mwt[px * 9 + t];
    const ushort* s0 = xTb + mo.x;
    const ushort* s1 = xTb + mo.y;
    const ushort* s2 = xTb + mo.z;
    const ushort* s3 = xTb + mo.w;
#pragma unroll
    for (int cc = 0; cc < 8; ++cc) {
      const int ca = cc * 32 + kg8;
      int4 A0 = *(const int4*)(s0 + ca);
      int4 A1 = *(const int4*)(s1 + ca);
      int4 A2 = *(const int4*)(s2 + ca);
      int4 A3 = *(const int4*)(s3 + ca);
      int4 F;
      F.x = packpair(wt, A0, A1, A2, A3, 0);
      F.y = packpair(wt, A0, A1, A2, A3, 1);
      F.z = packpair(wt, A0, A1, A2, A3, 2);
      F.w = packpair(wt, A0, A1, A2, A3, 3);
      bf16x8 af = *reinterpret_cast<const bf16x8*>(&F);
      const ushort* bs = bpl + (size_t)(t * 8 + cc) * 8192;
#pragma unroll
      for (int ni = 0; ni < 16; ++ni) {
        int4 Bv = *(const int4*)(bs + ni * 512);
        bf16x8 bfr = *reinterpret_cast<const bf16x8*>(&Bv);
        acc[ni] = __builtin_amdgcn_mfma_f32_16x16x32_bf16(af, bfr, acc[ni], 0, 0, 0);
      }
    }
    __syncthreads();   // lockstep: keep the 8 waves/CU in the same B window
  }

  // epilogue: verified D map (pixel = 4*kg + r within my 16, oc = ni*16 + nl)
#pragma unroll
  for (int ni = 0; ni < 16; ++ni) {
    int o = ni * 16 + nl;
    float cbv = convb[o];
    float* op = out + (size_t)(b * COUT + o) * HW + h * WW + w0 + wid * 16;
#pragma unroll
    for (int r = 0; r < 4; ++r)
      op[kg * 4 + r] = acc[ni][r] + cbv;
  }
}

extern "C" void kernel_launch(void* const* d_in, const int* in_sizes, int n_in,
                              void* d_out, int out_size, void* d_ws, size_t ws_size,
                              hipStream_t stream) {
  const float* x     = (const float*)d_in[0];
  const float* ctr   = (const float*)d_in[1];
  const float* scale = (const float*)d_in[2];
  const float* offw  = (const float*)d_in[3];
  const float* offb  = (const float*)d_in[4];
  const float* mskw  = (const float*)d_in[5];
  const float* mskb  = (const float*)d_in[6];
  const float* cw    = (const float*)d_in[7];
  const float* cb    = (const float*)d_in[8];
  float* out = (float*)d_out;

  char* ws = (char*)d_ws;
  ushort* xT  = (ushort*)ws;                 // 16,777,216 B
  ushort* Bm2 = (ushort*)(ws + 16777216);    //  1,179,648 B

  k_transpose<<<dim3(1024), dim3(256), 0, stream>>>(x, xT);
  k_packw2<<<dim3(2304), dim3(256), 0, stream>>>(cw, Bm2);
  k_mfma8<<<dim3(512), dim3(256), 0, stream>>>(xT, Bm2, scale, ctr, offw, offb,
                                               mskw, mskb, cb, out);
}

// Round 17
// 157.302 us; speedup vs baseline: 1.1005x; 1.1005x over previous
//
#include <hip/hip_runtime.h>

// FeatureAdaptation (deformable conv): B=2, CHI=CHO=256, H=W=128, K=9.
// R17: arithmetic-intensity round. M=32 per wave (2 A-frags, 32 MFMA/step):
// halves per-CU B volume (the R15/R16-measured dominant term) and doubles
// MFMA cover over gather latency. Fragment maps = R10/R13 (twice-proven) x
// R15's fragment-linear B (proven). Producer==consumer, no in-loop barriers.

typedef __bf16 bf16x8 __attribute__((ext_vector_type(8)));
typedef float f32x4 __attribute__((ext_vector_type(4)));

#define HH 128
#define WW 128
#define CIN 256
#define COUT 256
#define KK9 9
#define HW (HH * WW)            // 16384
#define KDIM (KK9 * CIN)        // 2304
#define XT_PER_B (HW * CIN)

__device__ __forceinline__ ushort f2bf(float f) {
  union { float f; unsigned u; } v; v.f = f;
  unsigned u = v.u;
  u += 0x7FFFu + ((u >> 16) & 1u);   // RNE
  return (ushort)(u >> 16);
}
__device__ __forceinline__ float bf2f(ushort h) {
  return __uint_as_float(((unsigned)h) << 16);
}
// bf16 element e (0..7) of an int4 viewed as 8 bf16, as f32 (e compile-time)
__device__ __forceinline__ float bfsel(const int4 v, int e) {
  int w = ((e >> 1) == 0) ? v.x : ((e >> 1) == 1) ? v.y
        : ((e >> 1) == 2) ? v.z : v.w;
  return __uint_as_float((e & 1) ? ((unsigned)w & 0xffff0000u)
                                 : ((unsigned)w << 16));
}
__device__ __forceinline__ int packpair(const float4 wt, const int4 a0,
                                        const int4 a1, const int4 a2,
                                        const int4 a3, int q) {
  float vl = wt.x * bfsel(a0, 2 * q)     + wt.y * bfsel(a1, 2 * q)
           + wt.z * bfsel(a2, 2 * q)     + wt.w * bfsel(a3, 2 * q);
  float vh = wt.x * bfsel(a0, 2 * q + 1) + wt.y * bfsel(a1, 2 * q + 1)
           + wt.z * bfsel(a2, 2 * q + 1) + wt.w * bfsel(a3, 2 * q + 1);
  return (int)((unsigned)f2bf(vl) | ((unsigned)f2bf(vh) << 16));
}

// ---------------- x (B,C,H,W) f32  ->  xT (B,H,W,C) bf16 ----------------
__global__ __launch_bounds__(256) void k_transpose(const float* __restrict__ x,
                                                   ushort* __restrict__ xT) {
  __shared__ ushort tile[64][130];
  const int bid = blockIdx.x;
  const int y  = bid & 127;
  const int t  = bid >> 7;
  const int cb = t & 3;
  const int b  = t >> 2;
  const int xl = threadIdx.x & 127;
  const int ch = threadIdx.x >> 7;
  const float* src = x + (size_t)(b * CIN + cb * 64) * HW + y * WW + xl;
#pragma unroll
  for (int i = 0; i < 32; ++i) {
    int c = ch * 32 + i;
    tile[c][xl] = f2bf(src[(size_t)c * HW]);
  }
  __syncthreads();
  const int c  = threadIdx.x & 63;
  const int xh = threadIdx.x >> 6;
  ushort* dst = xT + (size_t)b * XT_PER_B + (size_t)(y * WW) * CIN + cb * 64 + c;
#pragma unroll
  for (int i = 0; i < 32; ++i) {
    int xx = xh * 32 + i;
    dst[(size_t)xx * CIN] = tile[c][xx];
  }
}

// ------- conv_w (O,C,3,3) -> Bm2 fragment-linear bf16 (R15-verified) -------
__global__ __launch_bounds__(256) void k_packw2(const float* __restrict__ cw,
                                                ushort* __restrict__ Bm2) {
  int idx = blockIdx.x * 256 + threadIdx.x;   // < 589824
  int e  = idx & 7;
  int l  = (idx >> 3) & 63;
  int f  = idx >> 9;          // frag id: (s*16 + ni), s = t*8+cc
  int ni = f & 15;
  int s  = f >> 4;            // 0..71
  int cc = s & 7;
  int t  = s >> 3;
  int nl = l & 15;
  int kg = l >> 4;
  int o  = ni * 16 + nl;
  int c  = cc * 32 + kg * 8 + e;
  Bm2[idx] = f2bf(cw[(o * CIN + c) * KK9 + t]);
}

// ---------------- 1-wave M=32 gather + implicit MFMA GEMM ----------------
// grid 1024 (XCD-swizzled); block 64 (1 wave). Block: 32 px x 256 out-ch.
__global__ __launch_bounds__(64) void k_mfma9(
    const ushort* __restrict__ xT, const ushort* __restrict__ Bm2,
    const float* __restrict__ scale, const float* __restrict__ ctr,
    const float* __restrict__ offw, const float* __restrict__ offb,
    const float* __restrict__ mskw, const float* __restrict__ mskb,
    const float* __restrict__ convb, float* __restrict__ out) {
  __shared__ int4   moff[32 * KK9];
  __shared__ float4 mwt[32 * KK9];

  const int lane = threadIdx.x;     // 0..63
  // bijective XCD swizzle (1024 % 8 == 0)
  const int mb  = ((blockIdx.x & 7) << 7) | (blockIdx.x >> 3);
  const int b   = mb >> 9;
  const int rem = mb & 511;
  const int h   = rem >> 2;
  const int w0  = (rem & 3) << 5;   // 32-pixel row segment

  // ---- prologue: per (pixel,tap) bilinear metadata (R2-verified math)
  for (int idx = lane; idx < 32 * KK9; idx += 64) {
    int p = idx / 9;
    int k = idx - p * 9;
    int w = w0 + p;
    float sc = scale[b * HW + h * WW + w];
    float ct = ctr[b * HW + h * WW + w];
    float dy = sc * offw[2 * k]     + offb[2 * k];
    float dx = sc * offw[2 * k + 1] + offb[2 * k + 1];
    float mk = 1.0f / (1.0f + __expf(-(ct * mskw[k] + mskb[k])));
    float ys = (float)(h + (k / 3) - 1) + dy;
    float xs = (float)(w + (k % 3) - 1) + dx;
    float y0 = floorf(ys), x0 = floorf(xs);
    float wy1 = ys - y0, wx1 = xs - x0;
    float wy0 = 1.f - wy1, wx0 = 1.f - wx1;
    int offc[4]; float wtc[4];
#pragma unroll
    for (int a = 0; a < 2; ++a)
#pragma unroll
      for (int bb = 0; bb < 2; ++bb) {
        float yc = y0 + (float)a, xc = x0 + (float)bb;
        bool valid = (yc >= 0.f) && (yc <= 127.f) && (xc >= 0.f) && (xc <= 127.f);
        int yi = (int)fminf(fmaxf(yc, 0.f), 127.f);
        int xi = (int)fminf(fmaxf(xc, 0.f), 127.f);
        offc[a * 2 + bb] = (yi * WW + xi) * CIN;
        wtc[a * 2 + bb]  = (a ? wy1 : wy0) * (bb ? wx1 : wx0) * mk * (valid ? 1.f : 0.f);
      }
    moff[idx] = make_int4(offc[0], offc[1], offc[2], offc[3]);
    mwt[idx]  = make_float4(wtc[0], wtc[1], wtc[2], wtc[3]);
  }
  __syncthreads();

  const ushort* xTb = xT + (size_t)b * XT_PER_B;
  const int nl  = lane & 15;
  const int kg  = lane >> 4;
  const int kg8 = kg * 8;

  f32x4 acc0[16], acc1[16];
#pragma unroll
  for (int ni = 0; ni < 16; ++ni) {
    acc0[ni] = (f32x4){0.f, 0.f, 0.f, 0.f};
    acc1[ni] = (f32x4){0.f, 0.f, 0.f, 0.f};
  }

  // per-lane B base: fragment-linear (R15-verified)
  const ushort* bpl = Bm2 + (size_t)lane * 8;

  for (int t = 0; t < KK9; ++t) {
    // two pixel fragments: px0 = nl, px1 = 16 + nl (R10-verified geometry)
    const int4   mo0 = moff[nl * 9 + t];
    const float4 wt0 = mwt[nl * 9 + t];
    const int4   mo1 = moff[(16 + nl) * 9 + t];
    const float4 wt1 = mwt[(16 + nl) * 9 + t];
    const ushort* s00 = xTb + mo0.x;
    const ushort* s01 = xTb + mo0.y;
    const ushort* s02 = xTb + mo0.z;
    const ushort* s03 = xTb + mo0.w;
    const ushort* s10 = xTb + mo1.x;
    const ushort* s11 = xTb + mo1.y;
    const ushort* s12 = xTb + mo1.z;
    const ushort* s13 = xTb + mo1.w;
#pragma unroll
    for (int cc = 0; cc < 8; ++cc) {
      const int ca = cc * 32 + kg8;
      int4 A00 = *(const int4*)(s00 + ca);
      int4 A01 = *(const int4*)(s01 + ca);
      int4 A02 = *(const int4*)(s02 + ca);
      int4 A03 = *(const int4*)(s03 + ca);
      int4 A10 = *(const int4*)(s10 + ca);
      int4 A11 = *(const int4*)(s11 + ca);
      int4 A12 = *(const int4*)(s12 + ca);
      int4 A13 = *(const int4*)(s13 + ca);
      int4 F0, F1;
      F0.x = packpair(wt0, A00, A01, A02, A03, 0);
      F0.y = packpair(wt0, A00, A01, A02, A03, 1);
      F0.z = packpair(wt0, A00, A01, A02, A03, 2);
      F0.w = packpair(wt0, A00, A01, A02, A03, 3);
      F1.x = packpair(wt1, A10, A11, A12, A13, 0);
      F1.y = packpair(wt1, A10, A11, A12, A13, 1);
      F1.z = packpair(wt1, A10, A11, A12, A13, 2);
      F1.w = packpair(wt1, A10, A11, A12, A13, 3);
      bf16x8 af0 = *reinterpret_cast<const bf16x8*>(&F0);
      bf16x8 af1 = *reinterpret_cast<const bf16x8*>(&F1);
      const ushort* bs = bpl + (size_t)(t * 8 + cc) * 8192;
#pragma unroll
      for (int ni = 0; ni < 16; ++ni) {
        int4 Bv = *(const int4*)(bs + ni * 512);
        bf16x8 bfr = *reinterpret_cast<const bf16x8*>(&Bv);
        acc0[ni] = __builtin_amdgcn_mfma_f32_16x16x32_bf16(af0, bfr, acc0[ni], 0, 0, 0);
        acc1[ni] = __builtin_amdgcn_mfma_f32_16x16x32_bf16(af1, bfr, acc1[ni], 0, 0, 0);
      }
    }
  }

  // epilogue: verified D map (pixel = mi*16 + 4*kg + r, oc = ni*16 + nl)
#pragma unroll
  for (int ni = 0; ni < 16; ++ni) {
    int o = ni * 16 + nl;
    float cbv = convb[o];
    float* op = out + (size_t)(b * COUT + o) * HW + h * WW + w0;
#pragma unroll
    for (int r = 0; r < 4; ++r) {
      op[kg * 4 + r]      = acc0[ni][r] + cbv;
      op[16 + kg * 4 + r] = acc1[ni][r] + cbv;
    }
  }
}

extern "C" void kernel_launch(void* const* d_in, const int* in_sizes, int n_in,
                              void* d_out, int out_size, void* d_ws, size_t ws_size,
                              hipStream_t stream) {
  const float* x     = (const float*)d_in[0];
  const float* ctr   = (const float*)d_in[1];
  const float* scale = (const float*)d_in[2];
  const float* offw  = (const float*)d_in[3];
  const float* offb  = (const float*)d_in[4];
  const float* mskw  = (const float*)d_in[5];
  const float* mskb  = (const float*)d_in[6];
  const float* cw    = (const float*)d_in[7];
  const float* cb    = (const float*)d_in[8];
  float* out = (float*)d_out;

  char* ws = (char*)d_ws;
  ushort* xT  = (ushort*)ws;                 // 16,777,216 B
  ushort* Bm2 = (ushort*)(ws + 16777216);    //  1,179,648 B

  k_transpose<<<dim3(1024), dim3(256), 0, stream>>>(x, xT);
  k_packw2<<<dim3(2304), dim3(256), 0, stream>>>(cw, Bm2);
  k_mfma9<<<dim3(1024), dim3(64), 0, stream>>>(xT, Bm2, scale, ctr, offw, offb,
                                               mskw, mskb, cb, out);
}